// Round 1
// baseline (3557.804 us; speedup 1.0000x reference)
//
#include <hip/hip_runtime.h>
#include <hip/hip_bf16.h>

#define B_ 64
#define K_ 16
#define N_ 4096
#define C_ 384
#define M_ 4096
#define EPS_ 1e-8f

// ---------------------------------------------------------------------------
// init: copy input prototypes into ws and compute their norms
// ---------------------------------------------------------------------------
__global__ __launch_bounds__(384) void init_proto_kernel(
    const float* __restrict__ pin, float* __restrict__ proto,
    float* __restrict__ pnorm)
{
    const int bk = blockIdx.x;
    const int c  = threadIdx.x;            // 384 threads, c == channel
    float v = pin[(size_t)bk * C_ + c];
    proto[(size_t)bk * C_ + c] = v;
    float sq = v * v;
    #pragma unroll
    for (int m = 1; m <= 32; m <<= 1) sq += __shfl_xor(sq, m, 64);
    __shared__ float red[6];
    const int w = c >> 6, lane = c & 63;
    if (lane == 0) red[w] = sq;
    __syncthreads();
    if (c == 0) {
        float t = red[0] + red[1] + red[2] + red[3] + red[4] + red[5];
        pnorm[bk] = sqrtf(t);
    }
}

// ---------------------------------------------------------------------------
// sim: sim[b,k,n] = dot(proto[b,k],feats_row[n]) / max(pnorm*fnorm, EPS)
// One wave per row. lane = cc*4+kg ; kg = lane&3 (4 k-groups), cc = lane>>2
// (16 c-chunks of 24 floats). Each lane holds proto[kg*4+j][cc*24..+23] in
// 96 VGPRs; row loaded as float4 (4-way lane broadcast); reduce over cc via
// shfl_xor 4/8/16/32. Row norm computed in the same pass.
// ---------------------------------------------------------------------------
__global__ __launch_bounds__(256) void sim_kernel(
    const float* __restrict__ proto,   // [B,K,C]
    const float* __restrict__ pnorm,   // [B,K]
    const float* __restrict__ feats,   // rows [nrows, C], per-b stride bstride
    float* __restrict__ simout,        // [B,K,nrows]
    int nrows, long long bstride)
{
    const int b    = blockIdx.y;
    const int tile = blockIdx.x;           // 256 rows per block
    const int tid  = threadIdx.x;
    const int wave = tid >> 6;
    const int lane = tid & 63;
    const int kg   = lane & 3;
    const int cc   = lane >> 2;

    // prototype fragments in registers
    float4 pr[4][6];
    float  pn[4];
    const float* pb = proto + (size_t)b * K_ * C_;
    #pragma unroll
    for (int j = 0; j < 4; ++j) {
        const float* prow = pb + (size_t)(kg * 4 + j) * C_ + cc * 24;
        #pragma unroll
        for (int i = 0; i < 6; ++i) pr[j][i] = *(const float4*)(prow + i * 4);
        pn[j] = pnorm[b * K_ + kg * 4 + j];
    }

    const float* fb = feats + (size_t)b * bstride;
    const int nbase = tile * 256 + wave * 64;

    for (int r = 0; r < 64; ++r) {
        const int n = nbase + r;
        const float* frow = fb + (size_t)n * C_ + cc * 24;
        float4 f[6];
        #pragma unroll
        for (int i = 0; i < 6; ++i) f[i] = *(const float4*)(frow + i * 4);

        float s0 = 0.f, s1 = 0.f, s2 = 0.f, s3 = 0.f, nsq = 0.f;
        #pragma unroll
        for (int i = 0; i < 6; ++i) {
            nsq += f[i].x * f[i].x + f[i].y * f[i].y
                 + f[i].z * f[i].z + f[i].w * f[i].w;
            s0 += f[i].x * pr[0][i].x + f[i].y * pr[0][i].y
                + f[i].z * pr[0][i].z + f[i].w * pr[0][i].w;
            s1 += f[i].x * pr[1][i].x + f[i].y * pr[1][i].y
                + f[i].z * pr[1][i].z + f[i].w * pr[1][i].w;
            s2 += f[i].x * pr[2][i].x + f[i].y * pr[2][i].y
                + f[i].z * pr[2][i].z + f[i].w * pr[2][i].w;
            s3 += f[i].x * pr[3][i].x + f[i].y * pr[3][i].y
                + f[i].z * pr[3][i].z + f[i].w * pr[3][i].w;
        }
        // reduce over the 16 cc-lanes (cc bits are lane bits 2..5)
        #pragma unroll
        for (int m = 4; m <= 32; m <<= 1) {
            s0  += __shfl_xor(s0, m, 64);
            s1  += __shfl_xor(s1, m, 64);
            s2  += __shfl_xor(s2, m, 64);
            s3  += __shfl_xor(s3, m, 64);
            nsq += __shfl_xor(nsq, m, 64);
        }
        if (cc < 4) {                       // lanes 0..15 write all 16 k
            float v = s0;
            v = (cc == 1) ? s1 : v;
            v = (cc == 2) ? s2 : v;
            v = (cc == 3) ? s3 : v;
            float p = pn[0];
            p = (cc == 1) ? pn[1] : p;
            p = (cc == 2) ? pn[2] : p;
            p = (cc == 3) ? pn[3] : p;
            const float fn = sqrtf(nsq);
            const float denom = fmaxf(p * fn, EPS_);
            simout[((size_t)b * K_ + (kg * 4 + cc)) * (size_t)nrows + n] = v / denom;
        }
    }
}

// ---------------------------------------------------------------------------
// stats: per (b,k): density->tau->inv (from prev mask), rowmax, rowsum(exp)
// ---------------------------------------------------------------------------
__global__ __launch_bounds__(256) void stats_kernel(
    const float* __restrict__ sim,     // [B,K,N]
    const int* __restrict__ kmaxp,     // [B,N] previous-iteration assignment
    float* __restrict__ inv, float* __restrict__ rowmax,
    float* __restrict__ rowsum, int iter0)
{
    const int bk = blockIdx.x;
    const int b = bk >> 4, k = bk & 15;
    const int t = threadIdx.x;
    const float* row = sim + (size_t)bk * N_;
    const int*   km  = kmaxp + (size_t)b * N_;

    float4 v[4];
    float mx = -3.0e38f, ms = 0.f;
    int mc = 0;
    #pragma unroll
    for (int i = 0; i < 4; ++i) {
        v[i] = ((const float4*)row)[i * 256 + t];
        mx = fmaxf(mx, fmaxf(fmaxf(v[i].x, v[i].y), fmaxf(v[i].z, v[i].w)));
    }
    if (!iter0) {
        #pragma unroll
        for (int i = 0; i < 4; ++i) {
            const int4 kk = ((const int4*)km)[i * 256 + t];
            if (kk.x == k) { ms += v[i].x; mc++; }
            if (kk.y == k) { ms += v[i].y; mc++; }
            if (kk.z == k) { ms += v[i].z; mc++; }
            if (kk.w == k) { ms += v[i].w; mc++; }
        }
    }
    __shared__ float smx[4], sms[4];
    __shared__ int   smc[4];
    #pragma unroll
    for (int m = 1; m <= 32; m <<= 1) {
        mx = fmaxf(mx, __shfl_xor(mx, m, 64));
        ms += __shfl_xor(ms, m, 64);
        mc += __shfl_xor(mc, m, 64);
    }
    const int w = t >> 6, lane = t & 63;
    if (lane == 0) { smx[w] = mx; sms[w] = ms; smc[w] = mc; }
    __syncthreads();
    mx = fmaxf(fmaxf(smx[0], smx[1]), fmaxf(smx[2], smx[3]));
    ms = sms[0] + sms[1] + sms[2] + sms[3];
    mc = smc[0] + smc[1] + smc[2] + smc[3];

    float invv;
    if (iter0) {
        invv = 100.f;                     // 1/(temp*tau0) = 1/(0.1*0.1)
    } else {
        const float d   = (mc >= 1) ? (1.f - ms / (float)mc) : 1.f;
        const float tau = fmaxf(d, 1e-10f);
        invv = 1.f / (0.1f * tau);
    }
    float es = 0.f;
    #pragma unroll
    for (int i = 0; i < 4; ++i) {
        es += expf((v[i].x - mx) * invv) + expf((v[i].y - mx) * invv)
            + expf((v[i].z - mx) * invv) + expf((v[i].w - mx) * invv);
    }
    #pragma unroll
    for (int m = 1; m <= 32; m <<= 1) es += __shfl_xor(es, m, 64);
    __syncthreads();
    if (lane == 0) sms[w] = es;
    __syncthreads();
    if (t == 0) {
        rowmax[bk] = mx;
        rowsum[bk] = sms[0] + sms[1] + sms[2] + sms[3];
        inv[bk]    = invv;
    }
}

// ---------------------------------------------------------------------------
// argmax over k of softmax weight; emits winner index + winning weight
// ---------------------------------------------------------------------------
__global__ __launch_bounds__(256) void argmax_kernel(
    const float* __restrict__ sim, const float* __restrict__ rowmax,
    const float* __restrict__ rowsum, const float* __restrict__ inv,
    int* __restrict__ kmaxo, float* __restrict__ wselo)
{
    const int b = blockIdx.y;
    const int n = blockIdx.x * 256 + threadIdx.x;
    float best = -1.f;
    int bi = 0;
    #pragma unroll
    for (int k = 0; k < K_; ++k) {
        const float s = sim[((size_t)b * K_ + k) * N_ + n];
        const float w = expf((s - rowmax[b * K_ + k]) * inv[b * K_ + k])
                        / rowsum[b * K_ + k];
        if (w > best) { best = w; bi = k; }   // strict > keeps first (jnp tie rule)
    }
    kmaxo[(size_t)b * N_ + n] = bi;
    wselo[(size_t)b * N_ + n] = best;
}

// ---------------------------------------------------------------------------
// build deterministic per-(b,k) index lists (n ascending) via ballot/popc
// ---------------------------------------------------------------------------
__global__ __launch_bounds__(64) void build_lists_kernel(
    const int* __restrict__ kmax, const float* __restrict__ wsel,
    int* __restrict__ listn, float* __restrict__ listw,
    int* __restrict__ cnt, int* __restrict__ cntoff)
{
    const int b = blockIdx.x;
    const int lane = threadIdx.x;
    const int* km = kmax + (size_t)b * N_;
    const float* ws = wsel + (size_t)b * N_;
    const unsigned long long lt = (1ull << lane) - 1ull;

    int c[16];
    #pragma unroll
    for (int k = 0; k < 16; ++k) c[k] = 0;
    for (int base = 0; base < N_; base += 64) {
        const int kk = km[base + lane];
        #pragma unroll
        for (int k = 0; k < 16; ++k)
            c[k] += __popcll(__ballot(kk == k));
    }
    int off[16]; int acc = 0;
    #pragma unroll
    for (int k = 0; k < 16; ++k) { off[k] = acc; acc += c[k]; }
    if (lane == 0) {
        #pragma unroll
        for (int k = 0; k < 16; ++k) {
            cnt[b * K_ + k]    = c[k];
            cntoff[b * K_ + k] = off[k];
        }
    }
    int run[16];
    #pragma unroll
    for (int k = 0; k < 16; ++k) run[k] = off[k];
    for (int base = 0; base < N_; base += 64) {
        const int kk = km[base + lane];
        const float w = ws[base + lane];
        #pragma unroll
        for (int k = 0; k < 16; ++k) {
            const unsigned long long m = __ballot(kk == k);
            if (kk == k) {
                const int pos = run[k] + __popcll(m & lt);
                listn[(size_t)b * N_ + pos] = base + lane;
                listw[(size_t)b * N_ + pos] = w;
            }
            run[k] += __popcll(m);
        }
    }
}

// ---------------------------------------------------------------------------
// prototype update: proto[b,k,:] = sum over assigned rows of w * feats row
// one block per (b,k); 384 threads = one channel each; rows staged via LDS
// ---------------------------------------------------------------------------
__global__ __launch_bounds__(384) void update_kernel(
    const int* __restrict__ listn, const float* __restrict__ listw,
    const int* __restrict__ cnt, const int* __restrict__ cntoff,
    const float* __restrict__ feats, float* __restrict__ proto,
    float* __restrict__ pnorm)
{
    const int k = blockIdx.x, b = blockIdx.y;
    const int c = threadIdx.x;                  // 384
    const int bk = b * K_ + k;
    const int n0 = cntoff[bk];
    const int nc = cnt[bk];
    const int*   ln = listn + (size_t)b * N_ + n0;
    const float* lw = listw + (size_t)b * N_ + n0;
    const float* fb = feats + (size_t)b * N_ * C_;

    __shared__ int   sn[128];
    __shared__ float sw[128];
    float acc = 0.f;
    for (int chunk = 0; chunk < nc; chunk += 128) {
        const int m = min(128, nc - chunk);
        __syncthreads();
        if (c < m) { sn[c] = ln[chunk + c]; sw[c] = lw[chunk + c]; }
        __syncthreads();
        for (int i = 0; i < m; ++i)
            acc += sw[i] * fb[(size_t)sn[i] * C_ + c];
    }
    proto[(size_t)bk * C_ + c] = acc;

    float sq = acc * acc;
    #pragma unroll
    for (int m = 1; m <= 32; m <<= 1) sq += __shfl_xor(sq, m, 64);
    __shared__ float red[6];
    const int w = c >> 6, lane = c & 63;
    __syncthreads();
    if (lane == 0) red[w] = sq;
    __syncthreads();
    if (c == 0) {
        float t = red[0] + red[1] + red[2] + red[3] + red[4] + red[5];
        pnorm[bk] = sqrtf(t);
    }
}

// ---------------------------------------------------------------------------
extern "C" void kernel_launch(void* const* d_in, const int* in_sizes, int n_in,
                              void* d_out, int out_size, void* d_ws, size_t ws_size,
                              hipStream_t stream) {
    const float* pin   = (const float*)d_in[0];   // [B,K,C]
    const float* feats = (const float*)d_in[1];   // [B,N,C]
    const float* forg  = (const float*)d_in[2];   // [M,C]
    float* out = (float*)d_out;

    // workspace carve (floats unless noted), all offsets 4KB-aligned
    float* ws = (float*)d_ws;
    size_t o = 0;
    float* proto  = ws + o; o += (size_t)B_ * K_ * C_;   // 393216
    float* pnorm  = ws + o; o += 1024;
    float* inv    = ws + o; o += 1024;
    float* rowmax = ws + o; o += 1024;
    float* rowsum = ws + o; o += 1024;
    float* wsel   = ws + o; o += (size_t)B_ * N_;        // 262144
    float* listw  = ws + o; o += (size_t)B_ * N_;
    float* sim    = ws + o; o += (size_t)B_ * K_ * N_;   // 4194304
    int* kmax   = (int*)(ws + o); o += (size_t)B_ * N_;
    int* listn  = (int*)(ws + o); o += (size_t)B_ * N_;
    int* cnt    = (int*)(ws + o); o += 1024;
    int* cntoff = (int*)(ws + o); o += 1024;

    init_proto_kernel<<<B_ * K_, 384, 0, stream>>>(pin, proto, pnorm);
    sim_kernel<<<dim3(N_ / 256, B_), 256, 0, stream>>>(
        proto, pnorm, feats, sim, N_, (long long)N_ * C_);

    for (int it = 0; it < 5; ++it) {
        stats_kernel<<<B_ * K_, 256, 0, stream>>>(
            sim, kmax, inv, rowmax, rowsum, it == 0 ? 1 : 0);
        argmax_kernel<<<dim3(N_ / 256, B_), 256, 0, stream>>>(
            sim, rowmax, rowsum, inv, kmax, wsel);
        build_lists_kernel<<<B_, 64, 0, stream>>>(
            kmax, wsel, listn, listw, cnt, cntoff);
        update_kernel<<<dim3(K_, B_), 384, 0, stream>>>(
            listn, listw, cnt, cntoff, feats, proto, pnorm);
        if (it < 4) {
            sim_kernel<<<dim3(N_ / 256, B_), 256, 0, stream>>>(
                proto, pnorm, feats, sim, N_, (long long)N_ * C_);
        }
    }

    // final: sim against feats_org -> d_out sim region; copy final protos
    sim_kernel<<<dim3(M_ / 256, B_), 256, 0, stream>>>(
        proto, pnorm, forg, out + (size_t)B_ * K_ * C_, M_, 0LL);
    hipMemcpyAsync(out, proto, (size_t)B_ * K_ * C_ * sizeof(float),
                   hipMemcpyDeviceToDevice, stream);
}

// Round 2
// 2252.241 us; speedup vs baseline: 1.5797x; 1.5797x over previous
//
#include <hip/hip_runtime.h>
#include <hip/hip_bf16.h>

#define B_ 64
#define K_ 16
#define N_ 4096
#define C_ 384
#define M_ 4096
#define EPS_ 1e-8f

// ---------------------------------------------------------------------------
// init: copy input prototypes into ws and compute their norms
// ---------------------------------------------------------------------------
__global__ __launch_bounds__(384) void init_proto_kernel(
    const float* __restrict__ pin, float* __restrict__ proto,
    float* __restrict__ pnorm)
{
    const int bk = blockIdx.x;
    const int c  = threadIdx.x;            // 384 threads, c == channel
    float v = pin[(size_t)bk * C_ + c];
    proto[(size_t)bk * C_ + c] = v;
    float sq = v * v;
    #pragma unroll
    for (int m = 1; m <= 32; m <<= 1) sq += __shfl_xor(sq, m, 64);
    __shared__ float red[6];
    const int w = c >> 6, lane = c & 63;
    if (lane == 0) red[w] = sq;
    __syncthreads();
    if (c == 0) {
        float t = red[0] + red[1] + red[2] + red[3] + red[4] + red[5];
        pnorm[bk] = sqrtf(t);
    }
}

// ---------------------------------------------------------------------------
// sim: sim[b,k,n] = dot(proto[b,k],feats_row[n]) / max(pnorm*fnorm, EPS)
// One wave per row. lane = cc*4+kg ; kg = lane&3 (4 k-groups), cc = lane>>2
// (16 c-chunks of 24 floats). Each lane holds proto[kg*4+j][cc*24..+23] in
// 96 VGPRs; row loaded as float4 (4-way lane broadcast); reduce over cc via
// shfl_xor 4/8/16/32. Row norm computed in the same pass.
// ---------------------------------------------------------------------------
__global__ __launch_bounds__(256) void sim_kernel(
    const float* __restrict__ proto,   // [B,K,C]
    const float* __restrict__ pnorm,   // [B,K]
    const float* __restrict__ feats,   // rows [nrows, C], per-b stride bstride
    float* __restrict__ simout,        // [B,K,nrows]
    int nrows, long long bstride)
{
    const int b    = blockIdx.y;
    const int tile = blockIdx.x;           // 256 rows per block
    const int tid  = threadIdx.x;
    const int wave = tid >> 6;
    const int lane = tid & 63;
    const int kg   = lane & 3;
    const int cc   = lane >> 2;

    // prototype fragments in registers
    float4 pr[4][6];
    float  pn[4];
    const float* pb = proto + (size_t)b * K_ * C_;
    #pragma unroll
    for (int j = 0; j < 4; ++j) {
        const float* prow = pb + (size_t)(kg * 4 + j) * C_ + cc * 24;
        #pragma unroll
        for (int i = 0; i < 6; ++i) pr[j][i] = *(const float4*)(prow + i * 4);
        pn[j] = pnorm[b * K_ + kg * 4 + j];
    }

    const float* fb = feats + (size_t)b * bstride;
    const int nbase = tile * 256 + wave * 64;

    for (int r = 0; r < 64; ++r) {
        const int n = nbase + r;
        const float* frow = fb + (size_t)n * C_ + cc * 24;
        float4 f[6];
        #pragma unroll
        for (int i = 0; i < 6; ++i) f[i] = *(const float4*)(frow + i * 4);

        float s0 = 0.f, s1 = 0.f, s2 = 0.f, s3 = 0.f, nsq = 0.f;
        #pragma unroll
        for (int i = 0; i < 6; ++i) {
            nsq += f[i].x * f[i].x + f[i].y * f[i].y
                 + f[i].z * f[i].z + f[i].w * f[i].w;
            s0 += f[i].x * pr[0][i].x + f[i].y * pr[0][i].y
                + f[i].z * pr[0][i].z + f[i].w * pr[0][i].w;
            s1 += f[i].x * pr[1][i].x + f[i].y * pr[1][i].y
                + f[i].z * pr[1][i].z + f[i].w * pr[1][i].w;
            s2 += f[i].x * pr[2][i].x + f[i].y * pr[2][i].y
                + f[i].z * pr[2][i].z + f[i].w * pr[2][i].w;
            s3 += f[i].x * pr[3][i].x + f[i].y * pr[3][i].y
                + f[i].z * pr[3][i].z + f[i].w * pr[3][i].w;
        }
        // reduce over the 16 cc-lanes (cc bits are lane bits 2..5)
        #pragma unroll
        for (int m = 4; m <= 32; m <<= 1) {
            s0  += __shfl_xor(s0, m, 64);
            s1  += __shfl_xor(s1, m, 64);
            s2  += __shfl_xor(s2, m, 64);
            s3  += __shfl_xor(s3, m, 64);
            nsq += __shfl_xor(nsq, m, 64);
        }
        if (cc < 4) {                       // lanes 0..15 write all 16 k
            float v = s0;
            v = (cc == 1) ? s1 : v;
            v = (cc == 2) ? s2 : v;
            v = (cc == 3) ? s3 : v;
            float p = pn[0];
            p = (cc == 1) ? pn[1] : p;
            p = (cc == 2) ? pn[2] : p;
            p = (cc == 3) ? pn[3] : p;
            const float fn = sqrtf(nsq);
            const float denom = fmaxf(p * fn, EPS_);
            simout[((size_t)b * K_ + (kg * 4 + cc)) * (size_t)nrows + n] = v / denom;
        }
    }
}

// ---------------------------------------------------------------------------
// stats: per (b,k): density->tau->inv (from prev mask), rowmax, rowsum(exp)
// ---------------------------------------------------------------------------
__global__ __launch_bounds__(256) void stats_kernel(
    const float* __restrict__ sim,     // [B,K,N]
    const int* __restrict__ kmaxp,     // [B,N] previous-iteration assignment
    float* __restrict__ inv, float* __restrict__ rowmax,
    float* __restrict__ rowsum, int iter0)
{
    const int bk = blockIdx.x;
    const int b = bk >> 4, k = bk & 15;
    const int t = threadIdx.x;
    const float* row = sim + (size_t)bk * N_;
    const int*   km  = kmaxp + (size_t)b * N_;

    float4 v[4];
    float mx = -3.0e38f, ms = 0.f;
    int mc = 0;
    #pragma unroll
    for (int i = 0; i < 4; ++i) {
        v[i] = ((const float4*)row)[i * 256 + t];
        mx = fmaxf(mx, fmaxf(fmaxf(v[i].x, v[i].y), fmaxf(v[i].z, v[i].w)));
    }
    if (!iter0) {
        #pragma unroll
        for (int i = 0; i < 4; ++i) {
            const int4 kk = ((const int4*)km)[i * 256 + t];
            if (kk.x == k) { ms += v[i].x; mc++; }
            if (kk.y == k) { ms += v[i].y; mc++; }
            if (kk.z == k) { ms += v[i].z; mc++; }
            if (kk.w == k) { ms += v[i].w; mc++; }
        }
    }
    __shared__ float smx[4], sms[4];
    __shared__ int   smc[4];
    #pragma unroll
    for (int m = 1; m <= 32; m <<= 1) {
        mx = fmaxf(mx, __shfl_xor(mx, m, 64));
        ms += __shfl_xor(ms, m, 64);
        mc += __shfl_xor(mc, m, 64);
    }
    const int w = t >> 6, lane = t & 63;
    if (lane == 0) { smx[w] = mx; sms[w] = ms; smc[w] = mc; }
    __syncthreads();
    mx = fmaxf(fmaxf(smx[0], smx[1]), fmaxf(smx[2], smx[3]));
    ms = sms[0] + sms[1] + sms[2] + sms[3];
    mc = smc[0] + smc[1] + smc[2] + smc[3];

    float invv;
    if (iter0) {
        invv = 100.f;                     // 1/(temp*tau0) = 1/(0.1*0.1)
    } else {
        const float d   = (mc >= 1) ? (1.f - ms / (float)mc) : 1.f;
        const float tau = fmaxf(d, 1e-10f);
        invv = 1.f / (0.1f * tau);
    }
    float es = 0.f;
    #pragma unroll
    for (int i = 0; i < 4; ++i) {
        es += expf((v[i].x - mx) * invv) + expf((v[i].y - mx) * invv)
            + expf((v[i].z - mx) * invv) + expf((v[i].w - mx) * invv);
    }
    #pragma unroll
    for (int m = 1; m <= 32; m <<= 1) es += __shfl_xor(es, m, 64);
    __syncthreads();
    if (lane == 0) sms[w] = es;
    __syncthreads();
    if (t == 0) {
        rowmax[bk] = mx;
        rowsum[bk] = sms[0] + sms[1] + sms[2] + sms[3];
        inv[bk]    = invv;
    }
}

// ---------------------------------------------------------------------------
// argmax over k of softmax weight; emits winner index + winning weight
// ---------------------------------------------------------------------------
__global__ __launch_bounds__(256) void argmax_kernel(
    const float* __restrict__ sim, const float* __restrict__ rowmax,
    const float* __restrict__ rowsum, const float* __restrict__ inv,
    int* __restrict__ kmaxo, float* __restrict__ wselo)
{
    const int b = blockIdx.y;
    const int n = blockIdx.x * 256 + threadIdx.x;
    float best = -1.f;
    int bi = 0;
    #pragma unroll
    for (int k = 0; k < K_; ++k) {
        const float s = sim[((size_t)b * K_ + k) * N_ + n];
        const float w = expf((s - rowmax[b * K_ + k]) * inv[b * K_ + k])
                        / rowsum[b * K_ + k];
        if (w > best) { best = w; bi = k; }   // strict > keeps first (jnp tie rule)
    }
    kmaxo[(size_t)b * N_ + n] = bi;
    wselo[(size_t)b * N_ + n] = best;
}

// ---------------------------------------------------------------------------
// stage 1 of prototype update: each block owns 256 consecutive rows of one b,
// accumulates all 16 prototypes in registers (predicated FMA), writes partials.
// Deterministic, load-balanced, coalesced streaming of feats.
// ---------------------------------------------------------------------------
#define CHUNKS_ 16
#define ROWS_PER_CHUNK_ 256

__global__ __launch_bounds__(384) void partial_update_kernel(
    const int* __restrict__ kmax, const float* __restrict__ wsel,
    const float* __restrict__ feats,
    float* __restrict__ partial)       // [B, CHUNKS, K, C]
{
    const int chunk = blockIdx.x;          // 0..15
    const int b     = blockIdx.y;
    const int c     = threadIdx.x;         // channel

    float acc[K_];
    #pragma unroll
    for (int k = 0; k < K_; ++k) acc[k] = 0.f;

    const int nbase = chunk * ROWS_PER_CHUNK_;
    const int*   km = kmax + (size_t)b * N_ + nbase;
    const float* ws = wsel + (size_t)b * N_ + nbase;
    const float* fb = feats + ((size_t)b * N_ + nbase) * C_ + c;

    #pragma unroll 4
    for (int r = 0; r < ROWS_PER_CHUNK_; ++r) {
        const int   kk = km[r];            // wave-uniform -> scalar load
        const float w  = ws[r];            // wave-uniform -> scalar load
        const float f  = fb[(size_t)r * C_];
        #pragma unroll
        for (int k = 0; k < K_; ++k)
            acc[k] += (kk == k ? w : 0.f) * f;
    }

    float* pout = partial + (((size_t)b * CHUNKS_ + chunk) * K_) * C_ + c;
    #pragma unroll
    for (int k = 0; k < K_; ++k) pout[(size_t)k * C_] = acc[k];
}

// ---------------------------------------------------------------------------
// stage 2: reduce chunk partials -> proto, recompute pnorm
// ---------------------------------------------------------------------------
__global__ __launch_bounds__(384) void reduce_update_kernel(
    const float* __restrict__ partial, float* __restrict__ proto,
    float* __restrict__ pnorm)
{
    const int bk = blockIdx.x;
    const int b = bk >> 4, k = bk & 15;
    const int c = threadIdx.x;

    float acc = 0.f;
    #pragma unroll
    for (int ch = 0; ch < CHUNKS_; ++ch)
        acc += partial[(((size_t)b * CHUNKS_ + ch) * K_ + k) * C_ + c];
    proto[(size_t)bk * C_ + c] = acc;

    float sq = acc * acc;
    #pragma unroll
    for (int m = 1; m <= 32; m <<= 1) sq += __shfl_xor(sq, m, 64);
    __shared__ float red[6];
    const int w = c >> 6, lane = c & 63;
    if (lane == 0) red[w] = sq;
    __syncthreads();
    if (c == 0) {
        float t = red[0] + red[1] + red[2] + red[3] + red[4] + red[5];
        pnorm[bk] = sqrtf(t);
    }
}

// ---------------------------------------------------------------------------
extern "C" void kernel_launch(void* const* d_in, const int* in_sizes, int n_in,
                              void* d_out, int out_size, void* d_ws, size_t ws_size,
                              hipStream_t stream) {
    const float* pin   = (const float*)d_in[0];   // [B,K,C]
    const float* feats = (const float*)d_in[1];   // [B,N,C]
    const float* forg  = (const float*)d_in[2];   // [M,C]
    float* out = (float*)d_out;

    // workspace carve (floats)
    float* ws = (float*)d_ws;
    size_t o = 0;
    float* proto   = ws + o; o += (size_t)B_ * K_ * C_;            // 393216
    float* pnorm   = ws + o; o += 1024;
    float* inv     = ws + o; o += 1024;
    float* rowmax  = ws + o; o += 1024;
    float* rowsum  = ws + o; o += 1024;
    float* wsel    = ws + o; o += (size_t)B_ * N_;                 // 262144
    float* sim     = ws + o; o += (size_t)B_ * K_ * N_;            // 4194304
    float* partial = ws + o; o += (size_t)B_ * CHUNKS_ * K_ * C_;  // 6291456
    int* kmax = (int*)(ws + o); o += (size_t)B_ * N_;

    init_proto_kernel<<<B_ * K_, 384, 0, stream>>>(pin, proto, pnorm);
    sim_kernel<<<dim3(N_ / 256, B_), 256, 0, stream>>>(
        proto, pnorm, feats, sim, N_, (long long)N_ * C_);

    for (int it = 0; it < 5; ++it) {
        stats_kernel<<<B_ * K_, 256, 0, stream>>>(
            sim, kmax, inv, rowmax, rowsum, it == 0 ? 1 : 0);
        argmax_kernel<<<dim3(N_ / 256, B_), 256, 0, stream>>>(
            sim, rowmax, rowsum, inv, kmax, wsel);
        partial_update_kernel<<<dim3(CHUNKS_, B_), 384, 0, stream>>>(
            kmax, wsel, feats, partial);
        reduce_update_kernel<<<B_ * K_, 384, 0, stream>>>(
            partial, proto, pnorm);
        if (it < 4) {
            sim_kernel<<<dim3(N_ / 256, B_), 256, 0, stream>>>(
                proto, pnorm, feats, sim, N_, (long long)N_ * C_);
        }
    }

    // final: sim against feats_org -> d_out sim region; copy final protos
    sim_kernel<<<dim3(M_ / 256, B_), 256, 0, stream>>>(
        proto, pnorm, forg, out + (size_t)B_ * K_ * C_, M_, 0LL);
    hipMemcpyAsync(out, proto, (size_t)B_ * K_ * C_ * sizeof(float),
                   hipMemcpyDeviceToDevice, stream);
}

// Round 3
// 1727.785 us; speedup vs baseline: 2.0592x; 1.3035x over previous
//
#include <hip/hip_runtime.h>
#include <hip/hip_bf16.h>

#define B_ 64
#define K_ 16
#define N_ 4096
#define C_ 384
#define M_ 4096
#define EPS_ 1e-8f

// ---------------------------------------------------------------------------
// init: copy input prototypes into ws and compute their norms
// ---------------------------------------------------------------------------
__global__ __launch_bounds__(384) void init_proto_kernel(
    const float* __restrict__ pin, float* __restrict__ proto,
    float* __restrict__ pnorm)
{
    const int bk = blockIdx.x;
    const int c  = threadIdx.x;            // 384 threads, c == channel
    float v = pin[(size_t)bk * C_ + c];
    proto[(size_t)bk * C_ + c] = v;
    float sq = v * v;
    #pragma unroll
    for (int m = 1; m <= 32; m <<= 1) sq += __shfl_xor(sq, m, 64);
    __shared__ float red[6];
    const int w = c >> 6, lane = c & 63;
    if (lane == 0) red[w] = sq;
    __syncthreads();
    if (c == 0) {
        float t = red[0] + red[1] + red[2] + red[3] + red[4] + red[5];
        pnorm[bk] = sqrtf(t);
    }
}

// ---------------------------------------------------------------------------
// sim: sim[b,k,n] = dot(proto[b,k],feats_row[n]) / max(pnorm*fnorm, EPS)
// One wave per row. lane = cc*4+kg. Dot-partials folded pairwise:
//   foldA/B (xor 4): {s0,s1}->a, {s2,s3}->b ; foldC (xor 8): {a,b}->d ;
//   d += shfl_xor(16); d += shfl_xor(32)  => 5 shuffles per row (was 16).
// Lane<16 holds full dot for k = (lane&3)*4 + 2*((lane>>3)&1) + ((lane>>2)&1).
// NM: 0 = compute row norm + store to fnorm; 1 = load fnorm; 2 = compute only.
// ---------------------------------------------------------------------------
template <int NM>
__global__ __launch_bounds__(256) void sim_kernel(
    const float* __restrict__ proto,   // [B,K,C]
    const float* __restrict__ pnorm,   // [B,K]
    const float* __restrict__ feats,   // rows [nrows, C], per-b stride bstride
    float* __restrict__ fnorm,         // [B,nrows] (store NM=0 / load NM=1)
    float* __restrict__ simout,        // [B,K,nrows]
    int nrows, long long bstride)
{
    const int b    = blockIdx.y;
    const int tile = blockIdx.x;           // 256 rows per block
    const int tid  = threadIdx.x;
    const int wave = tid >> 6;
    const int lane = tid & 63;
    const int kg   = lane & 3;
    const int cc   = lane >> 2;
    const int p    = cc & 1;
    const int q    = (cc >> 1) & 1;

    // writer-lane k mapping and its prototype norm
    const int k_w = (lane & 3) * 4 + 2 * ((lane >> 3) & 1) + ((lane >> 2) & 1);
    const float pn_w = pnorm[b * K_ + (k_w & 15)];

    // prototype fragments in registers: 4 k's x 24 channels
    float4 pr[4][6];
    const float* pb = proto + (size_t)b * K_ * C_;
    #pragma unroll
    for (int j = 0; j < 4; ++j) {
        const float* prow = pb + (size_t)(kg * 4 + j) * C_ + cc * 24;
        #pragma unroll
        for (int i = 0; i < 6; ++i) pr[j][i] = *(const float4*)(prow + i * 4);
    }

    const float* fb = feats + (size_t)b * bstride;
    const int nbase = tile * 256 + wave * 64;

    for (int r = 0; r < 64; ++r) {
        const int n = nbase + r;
        const float* frow = fb + (size_t)n * C_ + cc * 24;
        float4 f[6];
        #pragma unroll
        for (int i = 0; i < 6; ++i) f[i] = *(const float4*)(frow + i * 4);

        float s0 = 0.f, s1 = 0.f, s2 = 0.f, s3 = 0.f, nsq = 0.f;
        #pragma unroll
        for (int i = 0; i < 6; ++i) {
            if (NM != 1)
                nsq += f[i].x * f[i].x + f[i].y * f[i].y
                     + f[i].z * f[i].z + f[i].w * f[i].w;
            s0 += f[i].x * pr[0][i].x + f[i].y * pr[0][i].y
                + f[i].z * pr[0][i].z + f[i].w * pr[0][i].w;
            s1 += f[i].x * pr[1][i].x + f[i].y * pr[1][i].y
                + f[i].z * pr[1][i].z + f[i].w * pr[1][i].w;
            s2 += f[i].x * pr[2][i].x + f[i].y * pr[2][i].y
                + f[i].z * pr[2][i].z + f[i].w * pr[2][i].w;
            s3 += f[i].x * pr[3][i].x + f[i].y * pr[3][i].y
                + f[i].z * pr[3][i].z + f[i].w * pr[3][i].w;
        }
        // fold A: merge {s0,s1} across cc bit0 (lane bit2)
        float sendA = p ? s0 : s1;
        float recvA = __shfl_xor(sendA, 4, 64);
        float a = (p ? s1 : s0) + recvA;
        // fold B: merge {s2,s3}
        float sendB = p ? s2 : s3;
        float recvB = __shfl_xor(sendB, 4, 64);
        float bb = (p ? s3 : s2) + recvB;
        // fold C: merge {a,b} across cc bit1 (lane bit3)
        float sendC = q ? a : bb;
        float recvC = __shfl_xor(sendC, 8, 64);
        float d = (q ? bb : a) + recvC;
        // plain reduce over remaining cc bits
        d += __shfl_xor(d, 16, 64);
        d += __shfl_xor(d, 32, 64);

        float fn;
        if (NM == 1) {
            fn = fnorm[(size_t)b * nrows + n];
        } else {
            #pragma unroll
            for (int m = 4; m <= 32; m <<= 1) nsq += __shfl_xor(nsq, m, 64);
            fn = sqrtf(nsq);
            if (NM == 0 && lane == 0) fnorm[(size_t)b * nrows + n] = fn;
        }
        if (lane < 16) {
            const float denom = fmaxf(pn_w * fn, EPS_);
            simout[((size_t)b * K_ + k_w) * (size_t)nrows + n] = d / denom;
        }
    }
}

// ---------------------------------------------------------------------------
// stats: per (b,k): density->tau->inv (from prev mask), rowmax, rowsum(exp)
// ---------------------------------------------------------------------------
__global__ __launch_bounds__(256) void stats_kernel(
    const float* __restrict__ sim,     // [B,K,N]
    const int* __restrict__ kmaxp,     // [B,N] previous-iteration assignment
    float* __restrict__ inv, float* __restrict__ rowmax,
    float* __restrict__ rowsum, int iter0)
{
    const int bk = blockIdx.x;
    const int b = bk >> 4, k = bk & 15;
    const int t = threadIdx.x;
    const float* row = sim + (size_t)bk * N_;
    const int*   km  = kmaxp + (size_t)b * N_;

    float4 v[4];
    float mx = -3.0e38f, ms = 0.f;
    int mc = 0;
    #pragma unroll
    for (int i = 0; i < 4; ++i) {
        v[i] = ((const float4*)row)[i * 256 + t];
        mx = fmaxf(mx, fmaxf(fmaxf(v[i].x, v[i].y), fmaxf(v[i].z, v[i].w)));
    }
    if (!iter0) {
        #pragma unroll
        for (int i = 0; i < 4; ++i) {
            const int4 kk = ((const int4*)km)[i * 256 + t];
            if (kk.x == k) { ms += v[i].x; mc++; }
            if (kk.y == k) { ms += v[i].y; mc++; }
            if (kk.z == k) { ms += v[i].z; mc++; }
            if (kk.w == k) { ms += v[i].w; mc++; }
        }
    }
    __shared__ float smx[4], sms[4];
    __shared__ int   smc[4];
    #pragma unroll
    for (int m = 1; m <= 32; m <<= 1) {
        mx = fmaxf(mx, __shfl_xor(mx, m, 64));
        ms += __shfl_xor(ms, m, 64);
        mc += __shfl_xor(mc, m, 64);
    }
    const int w = t >> 6, lane = t & 63;
    if (lane == 0) { smx[w] = mx; sms[w] = ms; smc[w] = mc; }
    __syncthreads();
    mx = fmaxf(fmaxf(smx[0], smx[1]), fmaxf(smx[2], smx[3]));
    ms = sms[0] + sms[1] + sms[2] + sms[3];
    mc = smc[0] + smc[1] + smc[2] + smc[3];

    float invv;
    if (iter0) {
        invv = 100.f;                     // 1/(temp*tau0) = 1/(0.1*0.1)
    } else {
        const float d   = (mc >= 1) ? (1.f - ms / (float)mc) : 1.f;
        const float tau = fmaxf(d, 1e-10f);
        invv = 1.f / (0.1f * tau);
    }
    float es = 0.f;
    #pragma unroll
    for (int i = 0; i < 4; ++i) {
        es += expf((v[i].x - mx) * invv) + expf((v[i].y - mx) * invv)
            + expf((v[i].z - mx) * invv) + expf((v[i].w - mx) * invv);
    }
    #pragma unroll
    for (int m = 1; m <= 32; m <<= 1) es += __shfl_xor(es, m, 64);
    __syncthreads();
    if (lane == 0) sms[w] = es;
    __syncthreads();
    if (t == 0) {
        rowmax[bk] = mx;
        rowsum[bk] = sms[0] + sms[1] + sms[2] + sms[3];
        inv[bk]    = invv;
    }
}

// ---------------------------------------------------------------------------
// argmax over k of softmax weight; emits winner index + winning weight
// ---------------------------------------------------------------------------
__global__ __launch_bounds__(256) void argmax_kernel(
    const float* __restrict__ sim, const float* __restrict__ rowmax,
    const float* __restrict__ rowsum, const float* __restrict__ inv,
    int* __restrict__ kmaxo, float* __restrict__ wselo)
{
    const int b = blockIdx.y;
    const int n = blockIdx.x * 256 + threadIdx.x;
    float best = -1.f;
    int bi = 0;
    #pragma unroll
    for (int k = 0; k < K_; ++k) {
        const float s = sim[((size_t)b * K_ + k) * N_ + n];
        const float w = expf((s - rowmax[b * K_ + k]) * inv[b * K_ + k])
                        / rowsum[b * K_ + k];
        if (w > best) { best = w; bi = k; }   // strict > keeps first (jnp tie rule)
    }
    kmaxo[(size_t)b * N_ + n] = bi;
    wselo[(size_t)b * N_ + n] = best;
}

// ---------------------------------------------------------------------------
// stage 1 of prototype update. Block = (chunk of 256 rows) x b. Thread t:
// rg = t/96 (row subgroup), ci = t%96 (float4 channel slot). Per iteration
// the block consumes 4 rows as pure float4 streams (flat index i*384+t).
// km/wsel staged once in LDS. 16 float4 register accumulators per thread;
// each rg writes its own partial slice (64 sub-chunks per b) -> deterministic.
// ---------------------------------------------------------------------------
#define CHUNKS_ 16
#define SUBCH_ 64          // CHUNKS_*4 sub-chunks per b

__global__ __launch_bounds__(384) void partial_update_kernel(
    const int* __restrict__ kmax, const float* __restrict__ wsel,
    const float* __restrict__ feats,
    float* __restrict__ partial)       // [B, SUBCH, K, C]
{
    const int chunk = blockIdx.x;          // 0..15
    const int b     = blockIdx.y;
    const int t     = threadIdx.x;         // 0..383
    const int rg    = t / 96;              // 0..3
    const int ci    = t % 96;              // float4 slot within row

    __shared__ int   skm[256];
    __shared__ float sws[256];
    if (t < 256) {
        skm[t] = kmax[(size_t)b * N_ + chunk * 256 + t];
        sws[t] = wsel[(size_t)b * N_ + chunk * 256 + t];
    }
    __syncthreads();

    float4 acc[K_];
    #pragma unroll
    for (int k = 0; k < K_; ++k) acc[k] = make_float4(0.f, 0.f, 0.f, 0.f);

    const float4* fb = (const float4*)(feats + ((size_t)b * N_ + chunk * 256) * C_);

    #pragma unroll 2
    for (int i = 0; i < 64; ++i) {
        const float4 f = fb[(size_t)i * 384 + t];
        const int    kk = skm[i * 4 + rg];
        const float  w  = sws[i * 4 + rg];
        #pragma unroll
        for (int k = 0; k < K_; ++k) {
            const float sel = (kk == k) ? w : 0.f;
            acc[k].x += sel * f.x;
            acc[k].y += sel * f.y;
            acc[k].z += sel * f.z;
            acc[k].w += sel * f.w;
        }
    }

    float4* po = (float4*)partial
               + ((size_t)(b * SUBCH_ + chunk * 4 + rg) * K_) * 96 + ci;
    #pragma unroll
    for (int k = 0; k < K_; ++k) po[(size_t)k * 96] = acc[k];
}

// ---------------------------------------------------------------------------
// stage 2: reduce sub-chunk partials -> proto, recompute pnorm
// ---------------------------------------------------------------------------
__global__ __launch_bounds__(384) void reduce_update_kernel(
    const float* __restrict__ partial, float* __restrict__ proto,
    float* __restrict__ pnorm)
{
    const int bk = blockIdx.x;
    const int b = bk >> 4, k = bk & 15;
    const int c = threadIdx.x;

    float acc = 0.f;
    #pragma unroll 8
    for (int ch = 0; ch < SUBCH_; ++ch)
        acc += partial[(((size_t)b * SUBCH_ + ch) * K_ + k) * C_ + c];
    proto[(size_t)bk * C_ + c] = acc;

    float sq = acc * acc;
    #pragma unroll
    for (int m = 1; m <= 32; m <<= 1) sq += __shfl_xor(sq, m, 64);
    __shared__ float red[6];
    const int w = c >> 6, lane = c & 63;
    if (lane == 0) red[w] = sq;
    __syncthreads();
    if (c == 0) {
        float t = red[0] + red[1] + red[2] + red[3] + red[4] + red[5];
        pnorm[bk] = sqrtf(t);
    }
}

// ---------------------------------------------------------------------------
extern "C" void kernel_launch(void* const* d_in, const int* in_sizes, int n_in,
                              void* d_out, int out_size, void* d_ws, size_t ws_size,
                              hipStream_t stream) {
    const float* pin   = (const float*)d_in[0];   // [B,K,C]
    const float* feats = (const float*)d_in[1];   // [B,N,C]
    const float* forg  = (const float*)d_in[2];   // [M,C]
    float* out = (float*)d_out;

    // workspace carve (floats)
    float* ws = (float*)d_ws;
    size_t o = 0;
    float* proto   = ws + o; o += (size_t)B_ * K_ * C_;            // 393216
    float* pnorm   = ws + o; o += 1024;
    float* inv     = ws + o; o += 1024;
    float* rowmax  = ws + o; o += 1024;
    float* rowsum  = ws + o; o += 1024;
    float* wsel    = ws + o; o += (size_t)B_ * N_;                 // 262144
    float* fnorm   = ws + o; o += (size_t)B_ * N_;                 // 262144
    float* sim     = ws + o; o += (size_t)B_ * K_ * N_;            // 4194304
    float* partial = ws + o; o += (size_t)B_ * SUBCH_ * K_ * C_;   // 25165824
    int* kmax = (int*)(ws + o); o += (size_t)B_ * N_;

    init_proto_kernel<<<B_ * K_, 384, 0, stream>>>(pin, proto, pnorm);
    // pass 1: compute + store row norms
    sim_kernel<0><<<dim3(N_ / 256, B_), 256, 0, stream>>>(
        proto, pnorm, feats, fnorm, sim, N_, (long long)N_ * C_);

    for (int it = 0; it < 5; ++it) {
        stats_kernel<<<B_ * K_, 256, 0, stream>>>(
            sim, kmax, inv, rowmax, rowsum, it == 0 ? 1 : 0);
        argmax_kernel<<<dim3(N_ / 256, B_), 256, 0, stream>>>(
            sim, rowmax, rowsum, inv, kmax, wsel);
        partial_update_kernel<<<dim3(CHUNKS_, B_), 384, 0, stream>>>(
            kmax, wsel, feats, partial);
        reduce_update_kernel<<<B_ * K_, 384, 0, stream>>>(
            partial, proto, pnorm);
        if (it < 4) {
            sim_kernel<1><<<dim3(N_ / 256, B_), 256, 0, stream>>>(
                proto, pnorm, feats, fnorm, sim, N_, (long long)N_ * C_);
        }
    }

    // final: sim against feats_org -> d_out sim region (norms computed in-pass)
    sim_kernel<2><<<dim3(M_ / 256, B_), 256, 0, stream>>>(
        proto, pnorm, forg, fnorm, out + (size_t)B_ * K_ * C_, M_, 0LL);
    hipMemcpyAsync(out, proto, (size_t)B_ * K_ * C_ * sizeof(float),
                   hipMemcpyDeviceToDevice, stream);
}